// Round 4
// baseline (79.434 us; speedup 1.0000x reference)
//
#include <hip/hip_runtime.h>
#include <math.h>

// ECT layer: ect[b,t,r] = sum_{n: batch[n]==b} sigmoid(8*(lin[r] - <x_n,v_t>))
// N=100000, D=3, T=64, R=64, B=128, lin = linspace(-1.1,1.1,64), d = 2.2/63.
//
// Round-3 post-mortem: per-sigmoid evaluation is the floor (38us VALU issue =
// 4.1e8 v_rcp) and FETCH_SIZE=695MB exposed acc[16] scratch spills. New
// algorithm: the sigmoid depends only on (lin_r - nh) -> ECT is a 1-D
// convolution. Per (b, 16 t's) block:
//   1) CIC-deposit nh into per-t LDS histogram on a lin-aligned grid
//      (160 bins, spacing d, 63 zero-pad below). Linear split between the 2
//      neighboring bins == linear interpolation of sigmoid: per-node error
//      <= sig''max*d^2/8 ~ 9.4e-4 (sum < 1 absolute, threshold 15.28).
//   2) Convolve with the exact sigmoid table W (223 taps incl. saturated
//      ==1.0 region, so no prefix-sum needed), sliding 4-reg window.
// Segment bounds via in-kernel 64-ary ballot search (3 dependent loads).
// One dispatch, no ws, no memset (out fully overwritten), no atomics to HBM.

#define THREADS 256
#define BSEG 128
#define TQ 4            // blocks per b (16 t's each)
#define TPB 16          // directions per block
#define GBINS 160       // real histogram bins
#define PAD 63          // zero-pad below bin 0
#define HSTR 223        // padded row length = PAD + GBINS (odd -> bank spread)
#define WN 223          // sigmoid table entries
#define STEPS 148       // conv micro-steps: k = 111-s, s in [0,148)

#if __has_builtin(__builtin_amdgcn_exp2f)
#define EXP2F(x) __builtin_amdgcn_exp2f(x)
#else
#define EXP2F(x) exp2f(x)
#endif
#if __has_builtin(__builtin_amdgcn_rcpf)
#define RCPF(x) __builtin_amdgcn_rcpf(x)
#else
#define RCPF(x) (1.0f / (x))
#endif

// all-lane 64-ary lower_bound: first i with A[i] >= val (A ascending).
__device__ __forceinline__ int lb64(const int* __restrict__ A, int n, int val,
                                    int lane) {
    int lo = 0, hi = n;
    while (hi - lo > 64) {
        const long long span = hi - lo;
        const int p = lo + (int)((span * lane) >> 6);        // p0 = lo
        const unsigned long long m = __ballot(A[p] < val);   // contiguous ones
        const int c = __popcll(m);
        if (c == 0) { hi = lo; break; }                      // A[lo] >= val
        const int plast = lo + (int)((span * (c - 1)) >> 6);
        const int pnext = (c < 64) ? (lo + (int)((span * (long long)c) >> 6)) : hi;
        lo = plast + 1; hi = pnext;
    }
    const int span = hi - lo;
    const unsigned long long m = __ballot(lane < span && A[lo + lane] < val);
    return lo + __popcll(m);
}

__global__ __launch_bounds__(THREADS, 2) void ect_fused_kernel(
    const float* __restrict__ x,      // [N,3]
    const float* __restrict__ v,      // [3,64]
    const int*   __restrict__ batch,  // [N] sorted 0..127
    float* __restrict__ out,          // [128,64,64]
    int n, float inv_d, float bias, float negd8l2e)  // -8*d*log2(e)
{
    __shared__ float smem[TPB * HSTR + WN + 1];
    float* Wr = smem + TPB * HSTR;    // 16B-aligned (3568*4 % 16 == 0)

    const int tid  = threadIdx.x;
    const int lane = tid & 63;
    const int b    = blockIdx.x >> 2;
    const int tq   = blockIdx.x & 3;

    // zero hist rows (vectorized): 3568 floats = 892 float4
    {
        float4* z = (float4*)smem;
        for (int i = tid; i < (TPB * HSTR) / 4; i += THREADS)
            z[i] = make_float4(0.f, 0.f, 0.f, 0.f);
    }
    // reversed sigmoid table: Wr[i] = sigmoid(8*d*(111-i))  (exact at grid pts)
    for (int i = tid; i < WN; i += THREADS) {
        const float zz = (float)(111 - i) * negd8l2e;  // exp2(zz)=exp(-8d(111-i))
        Wr[i] = RCPF(1.0f + EXP2F(zz));
    }

    // segment bounds (all waves duplicate; overlaps with init issue)
    const int s0 = lb64(batch, n, b, lane);
    const int s1 = lb64(batch, n, b + 1, lane);

    __syncthreads();

    // ---- phase 1: CIC deposit into per-t histograms ----
    const int t_l = tid >> 4;          // 0..15
    const int ns  = tid & 15;          // node slot
    const int t   = tq * TPB + t_l;
    const float v0 = v[t], v1 = v[64 + t], v2 = v[128 + t];
    float* Hrow = smem + t_l * HSTR + PAD;

    for (int i = s0 + ns; i < s1; i += 16) {
        const float3 xx = *(const float3*)(x + 3 * (size_t)i);
        const float nh = fmaf(xx.x, v0, fmaf(xx.y, v1, xx.z * v2));
        float bin = fmaf(nh, inv_d, bias);          // (nh - umin)/d
        bin = fminf(fmaxf(bin, 0.0f), 158.999f);    // clamp: tails saturate
        const float g0f = floorf(bin);
        const float fr  = bin - g0f;
        const int   g0  = (int)g0f;
        atomicAdd(Hrow + g0,     1.0f - fr);        // ds_add_f32
        atomicAdd(Hrow + g0 + 1, fr);
    }

    __syncthreads();

    // ---- phase 2: out[r] = sum_g hist[g] * sigmoid(8*d*(r+48-g)) ----
    const int rq = tid & 15;
    const int r0 = rq * 4;
    const float* H = smem + t_l * HSTR;   // padded row base
    float w0 = H[r0], w1 = H[r0 + 1], w2 = H[r0 + 2], w3 = H[r0 + 3];
    float a0 = 0.f, a1 = 0.f, a2 = 0.f, a3 = 0.f;
    int pidx = r0 + 4;
    for (int s = 0; s < STEPS; s += 4) {
        const float4 q = *(const float4*)(Wr + s);   // uniform broadcast, aligned
        const float n0 = H[pidx], n1 = H[pidx + 1], n2 = H[pidx + 2], n3 = H[pidx + 3];
        a0 = fmaf(q.x, w0, a0); a1 = fmaf(q.x, w1, a1); a2 = fmaf(q.x, w2, a2); a3 = fmaf(q.x, w3, a3);
        a0 = fmaf(q.y, w1, a0); a1 = fmaf(q.y, w2, a1); a2 = fmaf(q.y, w3, a2); a3 = fmaf(q.y, n0, a3);
        a0 = fmaf(q.z, w2, a0); a1 = fmaf(q.z, w3, a1); a2 = fmaf(q.z, n0, a2); a3 = fmaf(q.z, n1, a3);
        a0 = fmaf(q.w, w3, a0); a1 = fmaf(q.w, n0, a1); a2 = fmaf(q.w, n1, a2); a3 = fmaf(q.w, n2, a3);
        w0 = n0; w1 = n1; w2 = n2; w3 = n3;
        pidx += 4;
    }
    float4* o = (float4*)(out + ((size_t)b * 64 + t) * 64 + r0);
    *o = make_float4(a0, a1, a2, a3);
}

extern "C" void kernel_launch(void* const* d_in, const int* in_sizes, int n_in,
                              void* d_out, int out_size, void* d_ws, size_t ws_size,
                              hipStream_t stream) {
    const float* x     = (const float*)d_in[0];
    const float* v     = (const float*)d_in[1];
    const int*   batch = (const int*)d_in[2];
    float*       out   = (float*)d_out;

    const int n = in_sizes[0] / 3;

    const double d = 2.2 / 63.0;
    const float inv_d    = (float)(1.0 / d);          // 28.63636...
    const float bias     = 79.5f;                     // (0-umin)/d = 31.5+48 exact
    const float negd8l2e = (float)(-8.0 * d * 1.4426950408889634);

    hipLaunchKernelGGL(ect_fused_kernel, dim3(BSEG * TQ), dim3(THREADS), 0,
                       stream, x, v, batch, out, n, inv_d, bias, negd8l2e);
}